// Round 1
// baseline (314.195 us; speedup 1.0000x reference)
//
#include <hip/hip_runtime.h>
#include <math.h>

namespace {
constexpr int BN = 512, HH = 64, WW = 128, CC = 3;
constexpr int OHH = 13, OWW = 26;
constexpr int FEATN = OHH * OWW * 64;  // 21632
constexpr int KCH = 416;               // K-chunk for fc0 GEMM
constexpr int NKS = FEATN / KCH;       // 52
}

// ---------------------------------------------------------------------------
// K1: avgpool(3x3,s1,SAME,count-normalized) -> conv0(3x3,s5,pad0) -> relu
//     conv1(5x5,s5,padT0 B1 L1 R1) on raw x -> relu ; concat -> feat
// one block per (b, oh); feat layout [b][(oh*26+ow)*64 + ch]
// ---------------------------------------------------------------------------
__global__ __launch_bounds__(256) void k_feat(const float* __restrict__ x,
                                              const float* __restrict__ w0,
                                              const float* __restrict__ w1,
                                              float* __restrict__ feat) {
  const int b = blockIdx.x / OHH;
  const int oh = blockIdx.x % OHH;
  __shared__ float xs[6][130][3];   // rows oh*5-1 .. oh*5+4, cols padded +1
  __shared__ float pl[3][128][3];   // pooled rows oh*5 .. oh*5+2
  __shared__ float w0s[864];        // [kh][kw][ic][oc]
  __shared__ float w1s[2400];
  const int t = threadIdx.x;
  for (int i = t; i < 864; i += 256) w0s[i] = w0[i];
  for (int i = t; i < 2400; i += 256) w1s[i] = w1[i];
  const int r0g = oh * 5 - 1;
  for (int i = t; i < 6 * 130 * 3; i += 256) {
    int r = i / 390, rem = i - r * 390;
    int c = rem / 3, ic = rem - c * 3;
    int gr = r0g + r, gc = c - 1;
    float v = 0.f;
    if (gr >= 0 && gr < HH && gc >= 0 && gc < WW)
      v = x[(((size_t)b * HH + gr) * WW + gc) * CC + ic];
    xs[r][c][ic] = v;
  }
  __syncthreads();
  // pooled strip: TF avg_pool normalizes by VALID element count
  for (int i = t; i < 3 * 128 * 3; i += 256) {
    int pr = i / 384, rem = i - pr * 384;
    int c = rem / 3, ic = rem - c * 3;
    float s = 0.f;
#pragma unroll
    for (int dr = 0; dr < 3; ++dr)
#pragma unroll
      for (int dc = 0; dc < 3; ++dc) s += xs[pr + dr][c + dc][ic];
    int gr = oh * 5 + pr;
    int rc = min(gr + 1, HH - 1) - max(gr - 1, 0) + 1;
    int cc2 = min(c + 1, WW - 1) - max(c - 1, 0) + 1;
    pl[pr][c][ic] = s / (float)(rc * cc2);
  }
  __syncthreads();
  // thread owns one oc (0..31) and ow in {owb, owb+8, owb+16, owb+24}
  const int oc = t & 31;
  const int owb = t >> 5;
  int owc[4];
#pragma unroll
  for (int u = 0; u < 4; ++u) owc[u] = min(owb + 8 * u, OWW - 1);
  float a0[4] = {0.f, 0.f, 0.f, 0.f}, a1[4] = {0.f, 0.f, 0.f, 0.f};
#pragma unroll
  for (int kh = 0; kh < 3; ++kh)
#pragma unroll
    for (int kw = 0; kw < 3; ++kw)
#pragma unroll
      for (int ic = 0; ic < 3; ++ic) {
        float wv = w0s[((kh * 3 + kw) * 3 + ic) * 32 + oc];
#pragma unroll
        for (int u = 0; u < 4; ++u)
          a0[u] += pl[kh][owc[u] * 5 + kw][ic] * wv;
      }
#pragma unroll
  for (int kh = 0; kh < 5; ++kh)
#pragma unroll
    for (int kw = 0; kw < 5; ++kw)
#pragma unroll
      for (int ic = 0; ic < 3; ++ic) {
        float wv = w1s[((kh * 5 + kw) * 3 + ic) * 32 + oc];
#pragma unroll
        for (int u = 0; u < 4; ++u)
          a1[u] += xs[kh + 1][owc[u] * 5 + kw][ic] * wv;
      }
  float* fb = feat + (size_t)b * FEATN + oh * OWW * 64;
#pragma unroll
  for (int u = 0; u < 4; ++u) {
    int ow = owb + 8 * u;
    if (ow < OWW) {
      fb[ow * 64 + oc] = fmaxf(a0[u], 0.f);
      fb[ow * 64 + 32 + oc] = fmaxf(a1[u], 0.f);
    }
  }
}

// ---------------------------------------------------------------------------
// K2: fc0 partial GEMM. M=512, N=32, K=21632. grid = 8 Mtiles x 52 Ksplits.
// W chunk in LDS (broadcast reads); feat streamed float4 coalesced.
// ---------------------------------------------------------------------------
__global__ __launch_bounds__(256) void k_fc0(const float* __restrict__ feat,
                                             const float* __restrict__ w,
                                             float* __restrict__ part) {
  const int mt = blockIdx.x / NKS;
  const int ks = blockIdx.x % NKS;
  const int k0 = ks * KCH;
  __shared__ float wsh[KCH * 32];  // 53 KB
  const int t = threadIdx.x;
  {
    const float4* wg = (const float4*)(w + (size_t)k0 * 32);
    float4* wl = (float4*)wsh;
    for (int i = t; i < KCH * 8; i += 256) wl[i] = wg[i];
  }
  __syncthreads();
  const int r = t & 63;
  const int og = t >> 6;  // 0..3 -> oc block of 8
  const int m = mt * 64 + r;
  const float* fr = feat + (size_t)m * FEATN + k0;
  float acc[8] = {0.f, 0.f, 0.f, 0.f, 0.f, 0.f, 0.f, 0.f};
  for (int k = 0; k < KCH; k += 4) {
    float4 f = *(const float4*)(fr + k);
    float fv[4] = {f.x, f.y, f.z, f.w};
#pragma unroll
    for (int q = 0; q < 4; ++q) {
      float4 wa = *(const float4*)&wsh[(k + q) * 32 + og * 8];
      float4 wb = *(const float4*)&wsh[(k + q) * 32 + og * 8 + 4];
      acc[0] += fv[q] * wa.x; acc[1] += fv[q] * wa.y;
      acc[2] += fv[q] * wa.z; acc[3] += fv[q] * wa.w;
      acc[4] += fv[q] * wb.x; acc[5] += fv[q] * wb.y;
      acc[6] += fv[q] * wb.z; acc[7] += fv[q] * wb.w;
    }
  }
  float* po = part + ((size_t)ks * 512 + m) * 32 + og * 8;
  *(float4*)po = make_float4(acc[0], acc[1], acc[2], acc[3]);
  *(float4*)(po + 4) = make_float4(acc[4], acc[5], acc[6], acc[7]);
}

// ---------------------------------------------------------------------------
// K3: reduce K-split partials + bias + tanh -> hid; fc1 + tanh -> theta[512][6]
// ---------------------------------------------------------------------------
__global__ __launch_bounds__(256) void k_theta(const float* __restrict__ part,
                                               const float* __restrict__ b0,
                                               const float* __restrict__ w1,
                                               const float* __restrict__ b1,
                                               float* __restrict__ theta) {
  __shared__ float hid[8][32];
  const int t = threadIdx.x;
  const int bl = t >> 5, oc = t & 31;
  const int bb = blockIdx.x * 8 + bl;
  float s = 0.f;
  for (int ks = 0; ks < NKS; ++ks)
    s += part[(size_t)ks * 512 * 32 + bb * 32 + oc];
  hid[bl][oc] = tanhf(s + b0[oc]);
  __syncthreads();
  if (t < 48) {
    const int bl2 = t / 6, j = t - bl2 * 6;
    float s2 = b1[j];
#pragma unroll
    for (int o2 = 0; o2 < 32; ++o2) s2 += hid[bl2][o2] * w1[o2 * 6 + j];
    theta[(blockIdx.x * 8 + bl2) * 6 + j] = tanhf(s2);
  }
}

// ---------------------------------------------------------------------------
// K4: affine grid + bilinear sample (exact reference clip/extrapolate; Wd==1)
// 4 consecutive pixels per thread -> 3x float4 coalesced stores
// ---------------------------------------------------------------------------
__global__ __launch_bounds__(256) void k_sample(const float* __restrict__ x,
                                                const float* __restrict__ theta,
                                                float* __restrict__ out) {
  const int b = blockIdx.x >> 3;
  const int seg = blockIdx.x & 7;
  __shared__ float th[6];
  if (threadIdx.x < 6) th[threadIdx.x] = theta[b * 6 + threadIdx.x];
  __syncthreads();
  const float t00 = th[0], t01 = th[1], t02 = th[2];
  const float t10 = th[3], t11 = th[4], t12 = th[5];
  const int idx = seg * 1024 + threadIdx.x * 4;  // pixel index within image
  const int i = idx >> 7, j0 = idx & 127;
  const float yt = (float)i * (2.0f / 63.0f) - 1.0f;
  const float* xb = x + (size_t)b * (HH * WW * CC);
  float res[12];
#pragma unroll
  for (int p = 0; p < 4; ++p) {
    const float xt = (float)(j0 + p) * (2.0f / 127.0f) - 1.0f;
    const float gx = (t00 * xt + t01 * yt + t02 + 1.0f) * 64.0f;
    const float gy = (t10 * xt + t11 * yt + t12 + 1.0f) * 32.0f;
    const float fx = floorf(gx), fy = floorf(gy);
    const float x0f = fminf(fmaxf(fx, 0.f), 126.f);
    const float x1f = fminf(fmaxf(fx + 1.f, 1.f), 127.f);
    const float y0f = fminf(fmaxf(fy, 0.f), 62.f);
    const float y1f = fminf(fmaxf(fy + 1.f, 1.f), 63.f);
    const float wx0 = x1f - gx, wx1 = gx - x0f;
    const float wy0 = y1f - gy, wy1 = gy - y0f;
    const int xi0 = (int)x0f, xi1 = (int)x1f;
    const int yi0 = (int)y0f, yi1 = (int)y1f;
    const float* q00 = xb + (yi0 * WW + xi0) * 3;
    const float* q01 = xb + (yi1 * WW + xi0) * 3;
    const float* q10 = xb + (yi0 * WW + xi1) * 3;
    const float* q11 = xb + (yi1 * WW + xi1) * 3;
#pragma unroll
    for (int c = 0; c < 3; ++c)
      res[p * 3 + c] = wx0 * (wy0 * q00[c] + wy1 * q01[c]) +
                       wx1 * (wy0 * q10[c] + wy1 * q11[c]);
  }
  float4* o = (float4*)(out + ((size_t)b * 8192 + idx) * 3);
  o[0] = make_float4(res[0], res[1], res[2], res[3]);
  o[1] = make_float4(res[4], res[5], res[6], res[7]);
  o[2] = make_float4(res[8], res[9], res[10], res[11]);
}

extern "C" void kernel_launch(void* const* d_in, const int* in_sizes, int n_in,
                              void* d_out, int out_size, void* d_ws, size_t ws_size,
                              hipStream_t stream) {
  (void)in_sizes; (void)n_in; (void)out_size; (void)ws_size;
  const float* x   = (const float*)d_in[0];
  const float* w0  = (const float*)d_in[1];
  const float* w1  = (const float*)d_in[2];
  const float* fw0 = (const float*)d_in[3];
  const float* fb0 = (const float*)d_in[4];
  const float* fw1 = (const float*)d_in[5];
  const float* fb1 = (const float*)d_in[6];
  float* outp = (float*)d_out;
  // d_out doubles as scratch: feat (44.3 MB) + fc0 partials (3.4 MB) fit in
  // the 50.3 MB output buffer and are fully consumed before K4 overwrites.
  float* feat = outp;
  float* part = outp + (size_t)BN * FEATN;
  float* theta = (float*)d_ws;  // 12 KB — must survive K4's output writes
  k_feat  <<<BN * OHH, 256, 0, stream>>>(x, w0, w1, feat);
  k_fc0   <<<8 * NKS, 256, 0, stream>>>(feat, fw0, part);
  k_theta <<<64, 256, 0, stream>>>(part, fb0, fw1, fb1, theta);
  k_sample<<<BN * 8, 256, 0, stream>>>(x, theta, outp);
}

// Round 4
// 128.993 us; speedup vs baseline: 2.4358x; 2.4358x over previous
//
#include <hip/hip_runtime.h>
#include <math.h>

namespace {
constexpr int BN = 512, HH = 64, WW = 128, CC = 3;
constexpr int OHH = 13, OWW = 26;
constexpr int FEATN = OHH * OWW * 64;  // 21632
constexpr int KCH = 416;               // K-chunk for fc0 GEMM
constexpr int NKS = FEATN / KCH;       // 52
}

// ---------------------------------------------------------------------------
// K1: fused avgpool(3x3,s1,SAME,count-norm) -> conv0(3x3,s5) -> relu
//     and conv1(5x5,s5,padT0 B1 L1 R1) -> relu ; concat -> feat
// ONE THREAD PER OUTPUT POSITION (b,oh,ow). No LDS. Pixels in registers,
// weights via wave-uniform loads (scalarized to s_load) -> pure FMA loops.
// ---------------------------------------------------------------------------
__global__ __launch_bounds__(256, 3) void k_feat(const float* __restrict__ x,
                                                 const float* __restrict__ w0,
                                                 const float* __restrict__ w1,
                                                 float* __restrict__ feat) {
  const int p = blockIdx.x * 256 + threadIdx.x;  // 0 .. 173055
  const int b = p / 338;
  const int pos = p - b * 338;
  const int oh = pos / 26;
  const int ow = pos - oh * 26;
  const float* xb = x + (size_t)b * (HH * WW * CC);

  // footprint: rows oh*5-1 .. oh*5+4, cols ow*5-1 .. ow*5+3, zero-masked OOB
  float xv[6][15];
#pragma unroll
  for (int ri = 0; ri < 6; ++ri) {
    const int gr = oh * 5 - 1 + ri;
    const int grc = min(max(gr, 0), HH - 1);
    const bool rv = (gr >= 0) & (gr <= HH - 1);
    const float* rowp = xb + grc * (WW * CC);
#pragma unroll
    for (int pj = 0; pj < 5; ++pj) {
      const int gc = ow * 5 - 1 + pj;
      const int gcc = min(max(gc, 0), WW - 1);
      const bool v = rv & (gc >= 0) & (gc <= WW - 1);
      const float* pp = rowp + gcc * CC;
      const float f0 = pp[0], f1 = pp[1], f2 = pp[2];
      xv[ri][pj * 3 + 0] = v ? f0 : 0.f;
      xv[ri][pj * 3 + 1] = v ? f1 : 0.f;
      xv[ri][pj * 3 + 2] = v ? f2 : 0.f;
    }
  }

  // pooled taps for conv0: gr0=oh*5+kh (never bottom-clipped), gc0=ow*5+kw
  float inv[3][3];
#pragma unroll
  for (int kh = 0; kh < 3; ++kh)
#pragma unroll
    for (int kw = 0; kw < 3; ++kw) {
      const int rc = 3 - ((oh == 0 && kh == 0) ? 1 : 0);
      int cc2 = 3;
      if (ow == 0 && kw == 0) cc2 = 2;
      if (ow == OWW - 1 && kw == 2) cc2 = 2;
      inv[kh][kw] = 1.0f / (float)(rc * cc2);
    }
  float pooled[27];
#pragma unroll
  for (int kh = 0; kh < 3; ++kh)
#pragma unroll
    for (int kw = 0; kw < 3; ++kw)
#pragma unroll
      for (int ic = 0; ic < 3; ++ic) {
        float s = 0.f;
#pragma unroll
        for (int dr = 0; dr < 3; ++dr)
#pragma unroll
          for (int dc = 0; dc < 3; ++dc)
            s += xv[kh + dr][(kw + dc) * 3 + ic];
        pooled[(kh * 3 + kw) * 3 + ic] = s * inv[kh][kw];
      }

  float* fb = feat + (size_t)p * 64;

  // conv0: 32 oc in quads; weight address is wave-uniform -> s_load_dwordx4
#pragma unroll 1
  for (int qg = 0; qg < 8; ++qg) {
    float a0 = 0.f, a1 = 0.f, a2 = 0.f, a3 = 0.f;
#pragma unroll
    for (int tap = 0; tap < 27; ++tap) {
      const float pv = pooled[tap];
      const float4 wv = *(const float4*)(w0 + tap * 32 + qg * 4);
      a0 += pv * wv.x; a1 += pv * wv.y; a2 += pv * wv.z; a3 += pv * wv.w;
    }
    fb[qg * 4 + 0] = fmaxf(a0, 0.f);
    fb[qg * 4 + 1] = fmaxf(a1, 0.f);
    fb[qg * 4 + 2] = fmaxf(a2, 0.f);
    fb[qg * 4 + 3] = fmaxf(a3, 0.f);
  }

  // conv1: rows oh*5+kh -> xv[kh+1], cols ow*5-1+kw -> pixel kw
#pragma unroll 1
  for (int qg = 0; qg < 8; ++qg) {
    float a0 = 0.f, a1 = 0.f, a2 = 0.f, a3 = 0.f;
#pragma unroll
    for (int kh = 0; kh < 5; ++kh)
#pragma unroll
      for (int kw = 0; kw < 5; ++kw)
#pragma unroll
        for (int ic = 0; ic < 3; ++ic) {
          const float pv = xv[kh + 1][kw * 3 + ic];
          const int tap = (kh * 5 + kw) * 3 + ic;
          const float4 wv = *(const float4*)(w1 + tap * 32 + qg * 4);
          a0 += pv * wv.x; a1 += pv * wv.y; a2 += pv * wv.z; a3 += pv * wv.w;
        }
    fb[32 + qg * 4 + 0] = fmaxf(a0, 0.f);
    fb[32 + qg * 4 + 1] = fmaxf(a1, 0.f);
    fb[32 + qg * 4 + 2] = fmaxf(a2, 0.f);
    fb[32 + qg * 4 + 3] = fmaxf(a3, 0.f);
  }
}

// ---------------------------------------------------------------------------
// K2: fc0 partial GEMM. M=512, N=32, K=21632. grid = 8 Mtiles x 52 Ksplits.
// ---------------------------------------------------------------------------
__global__ __launch_bounds__(256) void k_fc0(const float* __restrict__ feat,
                                             const float* __restrict__ w,
                                             float* __restrict__ part) {
  const int mt = blockIdx.x / NKS;
  const int ks = blockIdx.x % NKS;
  const int k0 = ks * KCH;
  __shared__ float wsh[KCH * 32];  // 53 KB
  const int t = threadIdx.x;
  {
    const float4* wg = (const float4*)(w + (size_t)k0 * 32);
    float4* wl = (float4*)wsh;
    for (int i = t; i < KCH * 8; i += 256) wl[i] = wg[i];
  }
  __syncthreads();
  const int r = t & 63;
  const int og = t >> 6;  // 0..3 -> oc block of 8
  const int m = mt * 64 + r;
  const float* fr = feat + (size_t)m * FEATN + k0;
  float acc[8] = {0.f, 0.f, 0.f, 0.f, 0.f, 0.f, 0.f, 0.f};
  for (int k = 0; k < KCH; k += 4) {
    float4 f = *(const float4*)(fr + k);
    float fv[4] = {f.x, f.y, f.z, f.w};
#pragma unroll
    for (int q = 0; q < 4; ++q) {
      float4 wa = *(const float4*)&wsh[(k + q) * 32 + og * 8];
      float4 wb = *(const float4*)&wsh[(k + q) * 32 + og * 8 + 4];
      acc[0] += fv[q] * wa.x; acc[1] += fv[q] * wa.y;
      acc[2] += fv[q] * wa.z; acc[3] += fv[q] * wa.w;
      acc[4] += fv[q] * wb.x; acc[5] += fv[q] * wb.y;
      acc[6] += fv[q] * wb.z; acc[7] += fv[q] * wb.w;
    }
  }
  float* po = part + ((size_t)ks * 512 + m) * 32 + og * 8;
  *(float4*)po = make_float4(acc[0], acc[1], acc[2], acc[3]);
  *(float4*)(po + 4) = make_float4(acc[4], acc[5], acc[6], acc[7]);
}

// ---------------------------------------------------------------------------
// K3: reduce K-split partials + bias + tanh -> hid; fc1 + tanh -> theta
// ---------------------------------------------------------------------------
__global__ __launch_bounds__(256) void k_theta(const float* __restrict__ part,
                                               const float* __restrict__ b0,
                                               const float* __restrict__ w1,
                                               const float* __restrict__ b1,
                                               float* __restrict__ theta) {
  __shared__ float hid[8][32];
  const int t = threadIdx.x;
  const int bl = t >> 5, oc = t & 31;
  const int bb = blockIdx.x * 8 + bl;
  float s = 0.f;
  for (int ks = 0; ks < NKS; ++ks)
    s += part[(size_t)ks * 512 * 32 + bb * 32 + oc];
  hid[bl][oc] = tanhf(s + b0[oc]);
  __syncthreads();
  if (t < 48) {
    const int bl2 = t / 6, j = t - bl2 * 6;
    float s2 = b1[j];
#pragma unroll
    for (int o2 = 0; o2 < 32; ++o2) s2 += hid[bl2][o2] * w1[o2 * 6 + j];
    theta[(blockIdx.x * 8 + bl2) * 6 + j] = tanhf(s2);
  }
}

// ---------------------------------------------------------------------------
// K4: affine grid + bilinear sample (exact reference clip/extrapolate; Wd==1)
// ---------------------------------------------------------------------------
__global__ __launch_bounds__(256) void k_sample(const float* __restrict__ x,
                                                const float* __restrict__ theta,
                                                float* __restrict__ out) {
  const int b = blockIdx.x >> 3;
  const int seg = blockIdx.x & 7;
  __shared__ float th[6];
  if (threadIdx.x < 6) th[threadIdx.x] = theta[b * 6 + threadIdx.x];
  __syncthreads();
  const float t00 = th[0], t01 = th[1], t02 = th[2];
  const float t10 = th[3], t11 = th[4], t12 = th[5];
  const int idx = seg * 1024 + threadIdx.x * 4;  // pixel index within image
  const int i = idx >> 7, j0 = idx & 127;
  const float yt = (float)i * (2.0f / 63.0f) - 1.0f;
  const float* xb = x + (size_t)b * (HH * WW * CC);
  float res[12];
#pragma unroll
  for (int p = 0; p < 4; ++p) {
    const float xt = (float)(j0 + p) * (2.0f / 127.0f) - 1.0f;
    const float gx = (t00 * xt + t01 * yt + t02 + 1.0f) * 64.0f;
    const float gy = (t10 * xt + t11 * yt + t12 + 1.0f) * 32.0f;
    const float fx = floorf(gx), fy = floorf(gy);
    const float x0f = fminf(fmaxf(fx, 0.f), 126.f);
    const float x1f = fminf(fmaxf(fx + 1.f, 1.f), 127.f);
    const float y0f = fminf(fmaxf(fy, 0.f), 62.f);
    const float y1f = fminf(fmaxf(fy + 1.f, 1.f), 63.f);
    const float wx0 = x1f - gx, wx1 = gx - x0f;
    const float wy0 = y1f - gy, wy1 = gy - y0f;
    const int xi0 = (int)x0f, xi1 = (int)x1f;
    const int yi0 = (int)y0f, yi1 = (int)y1f;
    const float* q00 = xb + (yi0 * WW + xi0) * 3;
    const float* q01 = xb + (yi1 * WW + xi0) * 3;
    const float* q10 = xb + (yi0 * WW + xi1) * 3;
    const float* q11 = xb + (yi1 * WW + xi1) * 3;
#pragma unroll
    for (int c = 0; c < 3; ++c)
      res[p * 3 + c] = wx0 * (wy0 * q00[c] + wy1 * q01[c]) +
                       wx1 * (wy0 * q10[c] + wy1 * q11[c]);
  }
  float4* o = (float4*)(out + ((size_t)b * 8192 + idx) * 3);
  o[0] = make_float4(res[0], res[1], res[2], res[3]);
  o[1] = make_float4(res[4], res[5], res[6], res[7]);
  o[2] = make_float4(res[8], res[9], res[10], res[11]);
}

extern "C" void kernel_launch(void* const* d_in, const int* in_sizes, int n_in,
                              void* d_out, int out_size, void* d_ws, size_t ws_size,
                              hipStream_t stream) {
  (void)in_sizes; (void)n_in; (void)out_size; (void)ws_size;
  const float* x   = (const float*)d_in[0];
  const float* w0  = (const float*)d_in[1];
  const float* w1  = (const float*)d_in[2];
  const float* fw0 = (const float*)d_in[3];
  const float* fb0 = (const float*)d_in[4];
  const float* fw1 = (const float*)d_in[5];
  const float* fb1 = (const float*)d_in[6];
  float* outp = (float*)d_out;
  // d_out doubles as scratch: feat (44.3 MB) + fc0 partials (3.4 MB) fit in
  // the 50.3 MB output buffer and are fully consumed before K4 overwrites.
  float* feat = outp;
  float* part = outp + (size_t)BN * FEATN;
  float* theta = (float*)d_ws;  // 12 KB — survives K4's output writes
  k_feat  <<<(BN * 338) / 256, 256, 0, stream>>>(x, w0, w1, feat);
  k_fc0   <<<8 * NKS, 256, 0, stream>>>(feat, fw0, part);
  k_theta <<<64, 256, 0, stream>>>(part, fb0, fw1, fb1, theta);
  k_sample<<<BN * 8, 256, 0, stream>>>(x, theta, outp);
}